// Round 1
// baseline (524.657 us; speedup 1.0000x reference)
//
#include <hip/hip_runtime.h>
#include <stdint.h>

#define NN 50000
#define DD 64
#define EE 800000
#define CAP 64   // per-node slot capacity; P(Poisson(16) > 64) ~ 1e-20

// ---------------- kernel 0: zero the degree counters ----------------
__global__ void zero_deg(int* __restrict__ deg) {
    int i = blockIdx.x * blockDim.x + threadIdx.x;
    if (i < NN) deg[i] = 0;
}

// ---------------- kernel 1: bucket edges by destination ----------------
// slots[dst*CAP + p] = (w_bits << 32) | src
__global__ void scatter_edges(const int* __restrict__ ei, const float* __restrict__ ew,
                              int* __restrict__ deg, uint64_t* __restrict__ slots) {
    int e = blockIdx.x * blockDim.x + threadIdx.x;
    if (e >= EE) return;
    int src = ei[e];        // edge_index[0][e]
    int dst = ei[EE + e];   // edge_index[1][e]
    float w = ew[e];
    int p = atomicAdd(&deg[dst], 1);
    if (p < CAP) {
        uint64_t wb = (uint64_t)__float_as_uint(w);
        slots[(size_t)dst * CAP + p] = (wb << 32) | (uint32_t)(uint32_t)src;
    }
}

// ---------------- kernel 2: per-node per-channel lower median ----------------
// One wave (64 lanes) per node; lane d owns channel d.
// Stage deg weighted messages into wave-private LDS [CAP][64], then
// counting-selection for rank k=(deg-1)/2 with stable tie-break.
__global__ __launch_bounds__(128) void median_kernel(
    const float* __restrict__ x, const int* __restrict__ deg,
    const uint64_t* __restrict__ slots, float* __restrict__ out) {
    __shared__ float lds[2 * CAP * DD];   // 2 waves/block * 16 KB
    const int wid  = threadIdx.x >> 6;
    const int lane = threadIdx.x & 63;
    const int n = blockIdx.x * 2 + wid;
    if (n >= NN) return;

    int dg = deg[n];
    if (dg > CAP) dg = CAP;
    if (dg == 0) { out[(size_t)n * DD + lane] = 0.f; return; }

    float* col = lds + wid * (CAP * DD);

    // --- stage: lane j pre-loads slot j, broadcast via shuffle ---
    uint64_t s = 0;
    if (lane < dg) s = slots[(size_t)n * CAP + lane];
    int   src_l = (int)(uint32_t)(s & 0xffffffffu);
    float w_l   = __uint_as_float((uint32_t)(s >> 32));

    int j = 0;
    for (; j + 2 <= dg; j += 2) {
        int   s0 = __shfl(src_l, j);
        int   s1 = __shfl(src_l, j + 1);
        float w0 = __shfl(w_l, j);
        float w1 = __shfl(w_l, j + 1);
        float v0 = x[(size_t)s0 * DD + lane];   // coalesced 256B row load
        float v1 = x[(size_t)s1 * DD + lane];
        col[(j + 0) * DD + lane] = v0 * w0;
        col[(j + 1) * DD + lane] = v1 * w1;
    }
    if (j < dg) {
        int   s0 = __shfl(src_l, j);
        float w0 = __shfl(w_l, j);
        col[j * DD + lane] = x[(size_t)s0 * DD + lane] * w0;
    }
    // LDS region is wave-private: no __syncthreads needed; the compiler
    // inserts lgkmcnt waits before dependent ds_reads.

    // --- counting selection, 4 candidates at a time ---
    const int k = (dg - 1) >> 1;
    float med = 0.f;
    int c = 0;
    for (; c + 4 <= dg; c += 4) {
        float vc0 = col[(c + 0) * DD + lane];
        float vc1 = col[(c + 1) * DD + lane];
        float vc2 = col[(c + 2) * DD + lane];
        float vc3 = col[(c + 3) * DD + lane];
        int n0 = 0, n1 = 0, n2 = 0, n3 = 0;
        for (int i = 0; i < dg; ++i) {
            float vi = col[i * DD + lane];
            n0 += (vi < vc0) | ((vi == vc0) & (i < c + 0));
            n1 += (vi < vc1) | ((vi == vc1) & (i < c + 1));
            n2 += (vi < vc2) | ((vi == vc2) & (i < c + 2));
            n3 += (vi < vc3) | ((vi == vc3) & (i < c + 3));
        }
        if (n0 == k) med = vc0;
        if (n1 == k) med = vc1;
        if (n2 == k) med = vc2;
        if (n3 == k) med = vc3;
    }
    for (; c < dg; ++c) {
        float vc = col[c * DD + lane];
        int cnt = 0;
        for (int i = 0; i < dg; ++i) {
            float vi = col[i * DD + lane];
            cnt += (vi < vc) | ((vi == vc) & (i < c));
        }
        if (cnt == k) med = vc;
    }
    out[(size_t)n * DD + lane] = med;
}

extern "C" void kernel_launch(void* const* d_in, const int* in_sizes, int n_in,
                              void* d_out, int out_size, void* d_ws, size_t ws_size,
                              hipStream_t stream) {
    const float*  x  = (const float*)d_in[0];
    const int*    ei = (const int*)d_in[1];
    const float*  ew = (const float*)d_in[2];
    float* out = (float*)d_out;

    // workspace layout: [0, 256KB) deg counters, [256KB, ...) slot array
    int*      deg   = (int*)d_ws;
    uint64_t* slots = (uint64_t*)((char*)d_ws + (1 << 18));

    zero_deg<<<(NN + 255) / 256, 256, 0, stream>>>(deg);
    scatter_edges<<<(EE + 255) / 256, 256, 0, stream>>>(ei, ew, deg, slots);
    median_kernel<<<(NN + 1) / 2, 128, 0, stream>>>(x, deg, slots, out);
}

// Round 2
// 314.436 us; speedup vs baseline: 1.6686x; 1.6686x over previous
//
#include <hip/hip_runtime.h>
#include <stdint.h>

#define NN 50000
#define DD 64
#define EE 800000
#define CAP 64    // per-node slot capacity in global ws; P(Poisson(16) > 64) ~ 1e-20
#define TILE 32   // LDS rows per wave; deg > TILE takes the global fallback (P ~ 1e-4)

// ---------------- kernel 0: zero the degree counters ----------------
__global__ void zero_deg(int* __restrict__ deg) {
    int i = blockIdx.x * blockDim.x + threadIdx.x;
    if (i < NN) deg[i] = 0;
}

// ---------------- kernel 1: bucket edges by destination ----------------
// slots[dst*CAP + p] = (w_bits << 32) | src
__global__ void scatter_edges(const int* __restrict__ ei, const float* __restrict__ ew,
                              int* __restrict__ deg, uint64_t* __restrict__ slots) {
    int e = blockIdx.x * blockDim.x + threadIdx.x;
    if (e >= EE) return;
    int src = ei[e];        // edge_index[0][e]
    int dst = ei[EE + e];   // edge_index[1][e]
    float w = ew[e];
    int p = atomicAdd(&deg[dst], 1);
    if (p < CAP) {
        uint64_t wb = (uint64_t)__float_as_uint(w);
        slots[(size_t)dst * CAP + p] = (wb << 32) | (uint32_t)src;
    }
}

// ---------------- kernel 2: per-node per-channel lower median ----------------
// One wave per node, lane d = channel d. deg<=TILE: stage weighted messages in a
// wave-private LDS tile [TILE][64] (8 KB/wave -> 20 waves/CU), then counting
// selection for rank k=(deg-1)/2 in candidate groups of 8 (clamped indices, no
// scalar tail). deg>TILE (few nodes): recompute values from global per access.
__global__ __launch_bounds__(128) void median_kernel(
    const float* __restrict__ x, const int* __restrict__ deg,
    const uint64_t* __restrict__ slots, float* __restrict__ out) {
    __shared__ float lds[2 * TILE * DD];   // 16 KB/block -> 10 blocks/CU
    const int wid  = threadIdx.x >> 6;
    const int lane = threadIdx.x & 63;
    const int n = blockIdx.x * 2 + wid;
    if (n >= NN) return;

    int dg = deg[n];            // n is wave-uniform -> scalar load
    if (dg > CAP) dg = CAP;
    if (dg == 0) { out[(size_t)n * DD + lane] = 0.f; return; }

    // lane j holds slot j (src, w); broadcast via shuffle where needed
    uint64_t s = 0;
    if (lane < dg) s = slots[(size_t)n * CAP + lane];
    int   src_l = (int)(uint32_t)(s & 0xffffffffu);
    float w_l   = __uint_as_float((uint32_t)(s >> 32));

    const int k = (dg - 1) >> 1;
    float med = 0.f;

    if (dg <= TILE) {
        float* col = lds + wid * (TILE * DD);

        // --- stage: unroll 4 to pipeline the coalesced 256B row gathers ---
        int j = 0;
        for (; j + 4 <= dg; j += 4) {
            int   s0 = __shfl(src_l, j + 0), s1 = __shfl(src_l, j + 1);
            int   s2 = __shfl(src_l, j + 2), s3 = __shfl(src_l, j + 3);
            float w0 = __shfl(w_l, j + 0), w1 = __shfl(w_l, j + 1);
            float w2 = __shfl(w_l, j + 2), w3 = __shfl(w_l, j + 3);
            float v0 = x[(size_t)s0 * DD + lane];
            float v1 = x[(size_t)s1 * DD + lane];
            float v2 = x[(size_t)s2 * DD + lane];
            float v3 = x[(size_t)s3 * DD + lane];
            col[(j + 0) * DD + lane] = v0 * w0;
            col[(j + 1) * DD + lane] = v1 * w1;
            col[(j + 2) * DD + lane] = v2 * w2;
            col[(j + 3) * DD + lane] = v3 * w3;
        }
        for (; j < dg; ++j) {
            int   s0 = __shfl(src_l, j);
            float w0 = __shfl(w_l, j);
            col[j * DD + lane] = x[(size_t)s0 * DD + lane] * w0;
        }
        // wave-private LDS: no __syncthreads needed (compiler emits lgkmcnt waits)

        // --- counting selection, 8 clamped candidates per pass ---
        for (int c = 0; c < dg; c += 8) {
            int ci[8]; float vc[8]; int cnt[8];
            #pragma unroll
            for (int t = 0; t < 8; ++t) {
                ci[t] = min(c + t, dg - 1);
                vc[t] = col[ci[t] * DD + lane];
                cnt[t] = 0;
            }
            for (int i = 0; i < dg; ++i) {
                float vi = col[i * DD + lane];
                #pragma unroll
                for (int t = 0; t < 8; ++t)
                    cnt[t] += (vi < vc[t]) | ((vi == vc[t]) & (i < ci[t]));
            }
            #pragma unroll
            for (int t = 0; t < 8; ++t)
                if (cnt[t] == k) med = vc[t];
        }
    } else {
        // --- rare big-degree fallback: recompute x[src]*w from global (L2-hot) ---
        for (int c = 0; c < dg; c += 4) {
            int ci[4]; float vc[4]; int cnt[4];
            #pragma unroll
            for (int t = 0; t < 4; ++t) {
                ci[t] = min(c + t, dg - 1);
                int   sc = __shfl(src_l, ci[t]);
                float wc = __shfl(w_l, ci[t]);
                vc[t] = x[(size_t)sc * DD + lane] * wc;
                cnt[t] = 0;
            }
            for (int i = 0; i < dg; ++i) {
                int   si = __shfl(src_l, i);
                float wi = __shfl(w_l, i);
                float vi = x[(size_t)si * DD + lane] * wi;
                #pragma unroll
                for (int t = 0; t < 4; ++t)
                    cnt[t] += (vi < vc[t]) | ((vi == vc[t]) & (i < ci[t]));
            }
            #pragma unroll
            for (int t = 0; t < 4; ++t)
                if (cnt[t] == k) med = vc[t];
        }
    }

    out[(size_t)n * DD + lane] = med;
}

extern "C" void kernel_launch(void* const* d_in, const int* in_sizes, int n_in,
                              void* d_out, int out_size, void* d_ws, size_t ws_size,
                              hipStream_t stream) {
    const float*  x  = (const float*)d_in[0];
    const int*    ei = (const int*)d_in[1];
    const float*  ew = (const float*)d_in[2];
    float* out = (float*)d_out;

    // workspace layout: [0, 256KB) deg counters, [256KB, ...) slot array (25.6 MB)
    int*      deg   = (int*)d_ws;
    uint64_t* slots = (uint64_t*)((char*)d_ws + (1 << 18));

    zero_deg<<<(NN + 255) / 256, 256, 0, stream>>>(deg);
    scatter_edges<<<(EE + 255) / 256, 256, 0, stream>>>(ei, ew, deg, slots);
    median_kernel<<<(NN + 1) / 2, 128, 0, stream>>>(x, deg, slots, out);
}

// Round 3
// 241.179 us; speedup vs baseline: 2.1754x; 1.3037x over previous
//
#include <hip/hip_runtime.h>
#include <stdint.h>
#include <math.h>

#define NN 50000
#define DD 64
#define EE 800000
#define CAP 64    // per-node slot capacity; P(Poisson(16) > 64) ~ 1e-20

// ---------------- kernel 0: zero the degree counters ----------------
__global__ void zero_deg(int* __restrict__ deg) {
    int i = blockIdx.x * blockDim.x + threadIdx.x;
    if (i < NN) deg[i] = 0;
}

// ---------------- kernel 1: bucket edges by destination ----------------
// slots[dst*CAP + p] = (w_bits << 32) | src
__global__ void scatter_edges(const int* __restrict__ ei, const float* __restrict__ ew,
                              int* __restrict__ deg, uint64_t* __restrict__ slots) {
    int e = blockIdx.x * blockDim.x + threadIdx.x;
    if (e >= EE) return;
    int src = ei[e];        // edge_index[0][e]
    int dst = ei[EE + e];   // edge_index[1][e]
    float w = ew[e];
    int p = atomicAdd(&deg[dst], 1);
    if (p < CAP) {
        uint64_t wb = (uint64_t)__float_as_uint(w);
        slots[(size_t)dst * CAP + p] = (wb << 32) | (uint32_t)src;
    }
}

// ---------------- kernel 2: per-node per-channel lower median ----------------
// One wave per node, lane d = channel d. dg is wave-uniform -> branch to a
// compile-time bitonic network of padded size PW (pad +inf), values held in
// per-lane registers (no LDS). Full sort makes tie-break order irrelevant:
// the k-th smallest value is the lower median exactly.

template <int PW>
__device__ __forceinline__ float bitonic_median(float (&r)[PW], int k) {
    #pragma unroll
    for (int kk = 2; kk <= PW; kk <<= 1) {
        #pragma unroll
        for (int j = kk >> 1; j > 0; j >>= 1) {
            #pragma unroll
            for (int i = 0; i < PW; ++i) {
                int l = i ^ j;
                if (l > i) {
                    bool up = ((i & kk) == 0);
                    float a = r[i], b = r[l];
                    float lo = fminf(a, b), hi = fmaxf(a, b);
                    r[i] = up ? lo : hi;
                    r[l] = up ? hi : lo;
                }
            }
        }
    }
    float med = r[0];
    #pragma unroll
    for (int t = 1; t < PW; ++t)         // k is wave-uniform -> s_cmp + cndmask
        if (t == k) med = r[t];
    return med;
}

template <int PW>
__device__ __forceinline__ float gather_sort(const float* __restrict__ x, int lane,
                                             int dg, int k, int src_l, float w_l) {
    float r[PW];
    #pragma unroll
    for (int j = 0; j < PW; ++j) {       // PW independent coalesced 256B row loads
        int   sj = __shfl(src_l, j);     // lanes >= dg hold src=0 -> safe address
        float wj = __shfl(w_l, j);
        float v  = x[(size_t)sj * DD + lane] * wj;
        r[j] = (j < dg) ? v : INFINITY;  // dg uniform -> s_cmp + cndmask
    }
    return bitonic_median<PW>(r, k);
}

__global__ __launch_bounds__(256) void median_kernel(
    const float* __restrict__ x, const int* __restrict__ deg,
    const uint64_t* __restrict__ slots, float* __restrict__ out) {
    const int lane = threadIdx.x & 63;
    const int n = blockIdx.x * 4 + (threadIdx.x >> 6);
    if (n >= NN) return;

    int dg = deg[n];                     // wave-uniform
    if (dg > CAP) dg = CAP;
    if (dg == 0) { out[(size_t)n * DD + lane] = 0.f; return; }

    // lane j holds slot j (src, w)
    uint64_t s = 0;
    if (lane < dg) s = slots[(size_t)n * CAP + lane];
    int   src_l = (int)(uint32_t)(s & 0xffffffffu);
    float w_l   = __uint_as_float((uint32_t)(s >> 32));

    const int k = (dg - 1) >> 1;
    float med;

    if (dg == 1) {
        int s0 = __shfl(src_l, 0);
        med = x[(size_t)s0 * DD + lane] * __shfl(w_l, 0);
    } else if (dg <= 2)  { med = gather_sort<2>(x, lane, dg, k, src_l, w_l); }
    else if (dg <= 4)    { med = gather_sort<4>(x, lane, dg, k, src_l, w_l); }
    else if (dg <= 8)    { med = gather_sort<8>(x, lane, dg, k, src_l, w_l); }
    else if (dg <= 16)   { med = gather_sort<16>(x, lane, dg, k, src_l, w_l); }
    else if (dg <= 32)   { med = gather_sort<32>(x, lane, dg, k, src_l, w_l); }
    else {
        // rare big-degree fallback (P ~ 1e-4): counting selection from global
        med = 0.f;
        for (int c = 0; c < dg; c += 4) {
            int ci[4]; float vc[4]; int cnt[4];
            #pragma unroll
            for (int t = 0; t < 4; ++t) {
                ci[t] = min(c + t, dg - 1);
                int   sc = __shfl(src_l, ci[t]);
                float wc = __shfl(w_l, ci[t]);
                vc[t] = x[(size_t)sc * DD + lane] * wc;
                cnt[t] = 0;
            }
            for (int i = 0; i < dg; ++i) {
                int   si = __shfl(src_l, i);
                float wi = __shfl(w_l, i);
                float vi = x[(size_t)si * DD + lane] * wi;
                #pragma unroll
                for (int t = 0; t < 4; ++t)
                    cnt[t] += (vi < vc[t]) | ((vi == vc[t]) & (i < ci[t]));
            }
            #pragma unroll
            for (int t = 0; t < 4; ++t)
                if (cnt[t] == k) med = vc[t];
        }
    }

    out[(size_t)n * DD + lane] = med;
}

extern "C" void kernel_launch(void* const* d_in, const int* in_sizes, int n_in,
                              void* d_out, int out_size, void* d_ws, size_t ws_size,
                              hipStream_t stream) {
    const float*  x  = (const float*)d_in[0];
    const int*    ei = (const int*)d_in[1];
    const float*  ew = (const float*)d_in[2];
    float* out = (float*)d_out;

    // workspace layout: [0, 256KB) deg counters, [256KB, ...) slot array (25.6 MB)
    int*      deg   = (int*)d_ws;
    uint64_t* slots = (uint64_t*)((char*)d_ws + (1 << 18));

    zero_deg<<<(NN + 255) / 256, 256, 0, stream>>>(deg);
    scatter_edges<<<(EE + 255) / 256, 256, 0, stream>>>(ei, ew, deg, slots);
    median_kernel<<<(NN + 3) / 4, 256, 0, stream>>>(x, deg, slots, out);
}

// Round 4
// 205.793 us; speedup vs baseline: 2.5494x; 1.1719x over previous
//
#include <hip/hip_runtime.h>
#include <stdint.h>
#include <math.h>

#define NN 50000
#define DD 64
#define EE 800000
#define CAP 64    // per-node slot capacity; P(Poisson(16) > 64) ~ 1e-20

// ---------------- kernel 0: zero the degree counters ----------------
__global__ void zero_deg(int* __restrict__ deg) {
    int i = blockIdx.x * blockDim.x + threadIdx.x;
    if (i < NN) deg[i] = 0;
}

// ---------------- kernel 1: bucket edges by destination ----------------
// slots[dst*CAP + p] = (w_bits << 32) | src
__global__ void scatter_edges(const int* __restrict__ ei, const float* __restrict__ ew,
                              int* __restrict__ deg, uint64_t* __restrict__ slots) {
    int e = blockIdx.x * blockDim.x + threadIdx.x;
    if (e >= EE) return;
    int src = ei[e];        // edge_index[0][e]
    int dst = ei[EE + e];   // edge_index[1][e]
    float w = ew[e];
    int p = atomicAdd(&deg[dst], 1);
    if (p < CAP) {
        uint64_t wb = (uint64_t)__float_as_uint(w);
        slots[(size_t)dst * CAP + p] = (wb << 32) | (uint32_t)src;
    }
}

// ---------------- Batcher odd-even mergesort, all-constexpr indices ----------
// Template-recursive so every r[] access is a compile-time constant -> SROA
// keeps the whole array in VGPRs (no alloca, no scratch/LDS promotion).
__device__ __forceinline__ void cswap(float& a, float& b) {
    float lo = fminf(a, b);
    float hi = fmaxf(a, b);
    a = lo; b = hi;
}

template<int I, int END, int R, int STEP, int PW>
struct Pairs {
    static __device__ __forceinline__ void run(float (&r)[PW]) {
        if constexpr (I + R < END) {
            cswap(r[I], r[I + R]);
            Pairs<I + STEP, END, R, STEP, PW>::run(r);
        }
    }
};

template<int LO, int N, int R, int PW>
struct Merge {
    static __device__ __forceinline__ void run(float (&r)[PW]) {
        if constexpr (2 * R < N) {
            Merge<LO,     N, 2 * R, PW>::run(r);
            Merge<LO + R, N, 2 * R, PW>::run(r);
            Pairs<LO + R, LO + N, R, 2 * R, PW>::run(r);
        } else {
            cswap(r[LO], r[LO + R]);
        }
    }
};

template<int LO, int N, int PW>
struct Sorter {
    static __device__ __forceinline__ void run(float (&r)[PW]) {
        if constexpr (N > 1) {
            Sorter<LO,         N / 2, PW>::run(r);
            Sorter<LO + N / 2, N / 2, PW>::run(r);
            Merge<LO, N, 1, PW>::run(r);
        }
    }
};

// gather dg weighted rows (pad +inf to PW), sort, pick rank k.
// Caller guarantees dg in (PW/2, PW]  =>  k in [PW/4, PW/2-1]; restricting the
// selection chain to that range lets DCE prune comparators feeding other ranks.
template <int PW>
__device__ __forceinline__ float gather_sort(const float* __restrict__ x, int lane,
                                             int dg, int k, int src_l, float w_l) {
    float r[PW];
    #pragma unroll
    for (int j = 0; j < PW; ++j) {
        int   sj = __builtin_amdgcn_readlane(src_l, j);              // SGPR broadcast
        float wj = __uint_as_float((uint32_t)__builtin_amdgcn_readlane(
                       (int)__float_as_uint(w_l), j));
        float v = INFINITY;
        if (j < dg)                       // wave-uniform -> scalar branch, skips load
            v = x[(size_t)(uint32_t)sj * DD + lane] * wj;
        r[j] = v;
    }
    Sorter<0, PW, PW>::run(r);
    constexpr int KLO = PW / 4;
    constexpr int KHI = (PW / 2 > 0) ? PW / 2 - 1 : 0;
    float med = r[KLO];
    #pragma unroll
    for (int t = KLO + 1; t <= KHI; ++t)  // k wave-uniform -> s_cmp + cndmask
        if (t == k) med = r[t];
    return med;
}

// ---------------- kernel 2: per-node per-channel lower median ----------------
// One wave per node, lane d = channel d. dg wave-uniform -> dispatch to the
// matching power-of-2 network, values fully register-resident.
__global__ __launch_bounds__(256) void median_kernel(
    const float* __restrict__ x, const int* __restrict__ deg,
    const uint64_t* __restrict__ slots, float* __restrict__ out) {
    const int lane = threadIdx.x & 63;
    const int n = blockIdx.x * 4 + (threadIdx.x >> 6);
    if (n >= NN) return;

    int dg = deg[n];                     // wave-uniform
    if (dg > CAP) dg = CAP;
    if (dg == 0) { out[(size_t)n * DD + lane] = 0.f; return; }

    // lane j holds slot j (src, w)
    uint64_t s = 0;
    if (lane < dg) s = slots[(size_t)n * CAP + lane];
    int   src_l = (int)(uint32_t)(s & 0xffffffffu);
    float w_l   = __uint_as_float((uint32_t)(s >> 32));

    const int k = (dg - 1) >> 1;
    float med;

    if      (dg <= 2)  med = gather_sort<2>(x, lane, dg, k, src_l, w_l);
    else if (dg <= 4)  med = gather_sort<4>(x, lane, dg, k, src_l, w_l);
    else if (dg <= 8)  med = gather_sort<8>(x, lane, dg, k, src_l, w_l);
    else if (dg <= 16) med = gather_sort<16>(x, lane, dg, k, src_l, w_l);
    else if (dg <= 32) med = gather_sort<32>(x, lane, dg, k, src_l, w_l);
    else {
        // rare big-degree fallback (P ~ 1e-4): counting selection from global
        med = 0.f;
        for (int c = 0; c < dg; c += 4) {
            int ci[4]; float vc[4]; int cnt[4];
            #pragma unroll
            for (int t = 0; t < 4; ++t) {
                ci[t] = min(c + t, dg - 1);
                int   sc = __shfl(src_l, ci[t]);
                float wc = __shfl(w_l, ci[t]);
                vc[t] = x[(size_t)sc * DD + lane] * wc;
                cnt[t] = 0;
            }
            for (int i = 0; i < dg; ++i) {
                int   si = __shfl(src_l, i);
                float wi = __shfl(w_l, i);
                float vi = x[(size_t)si * DD + lane] * wi;
                #pragma unroll
                for (int t = 0; t < 4; ++t)
                    cnt[t] += (vi < vc[t]) | ((vi == vc[t]) & (i < ci[t]));
            }
            #pragma unroll
            for (int t = 0; t < 4; ++t)
                if (cnt[t] == k) med = vc[t];
        }
    }

    out[(size_t)n * DD + lane] = med;
}

extern "C" void kernel_launch(void* const* d_in, const int* in_sizes, int n_in,
                              void* d_out, int out_size, void* d_ws, size_t ws_size,
                              hipStream_t stream) {
    const float*  x  = (const float*)d_in[0];
    const int*    ei = (const int*)d_in[1];
    const float*  ew = (const float*)d_in[2];
    float* out = (float*)d_out;

    // workspace layout: [0, 256KB) deg counters, [256KB, ...) slot array (25.6 MB)
    int*      deg   = (int*)d_ws;
    uint64_t* slots = (uint64_t*)((char*)d_ws + (1 << 18));

    zero_deg<<<(NN + 255) / 256, 256, 0, stream>>>(deg);
    scatter_edges<<<(EE + 255) / 256, 256, 0, stream>>>(ei, ew, deg, slots);
    median_kernel<<<(NN + 3) / 4, 256, 0, stream>>>(x, deg, slots, out);
}